// Round 8
// baseline (108.096 us; speedup 1.0000x reference)
//
#include <hip/hip_runtime.h>
#include <math.h>

// Problem constants: B=1, H=8, S=512, D=64, P=32
#define HH 8
#define SS 512
#define DD 64
#define PP 32

// NOTE (R5/R6/R7 findings):
//  * Total dur_us carries ~81 us of fixed harness overhead — two ~40 us 0xAA
//    poison fills of the 256 MB workspace (fillBufferAligned at ~84% HBM peak)
//    inside the timed window. Kernel-side work is only ~22 us. Don't chase it.
//  * Keep ICNN weights TRANSPOSED in LDS ([in][out], pad 68) for the K-LOOPS:
//    natural [out][in] rows n0=4*tc at stride 68 collapse to banks {0,16} =
//    8-way conflict on every k-iter (R6: +10 us). One-time 8-way-conflicted
//    scalar writes at STAGING time are fine (~100 cyc/wave, once).
//  * No min-waves launch-bounds arg on the token kernel — R4 showed (256,4)
//    forces VGPR=64 and spills ~575 MB scratch (268 us).

__device__ __forceinline__ float softplusf(float x) {
    if (x > 20.f) return x;
    return log1pf(__expf(x));
}

// ---------------------------------------------------------------------------
// Kernel 1 v5: per-token compute with fused weight prep (transpose done at
// LDS-staging time; k-loops read transposed = conflict-free).
// Grid 384 blocks: role = bx>>7 (0=q: fq,phiq; 1=k: gk,phik,gkpart; 2=v: uexp).
// 32 tokens/block; 256 threads = 16x16 (tr,tc); thread tile = 2 tokens x
// (4 ICNN outputs + 2 phi outputs). W1/W2 staged sequentially through ONE
// LDS buffer; raw W2 prefetched into registers to hide global latency.
// ---------------------------------------------------------------------------
__global__ __launch_bounds__(256) void csm_token5(
    const float* __restrict__ q, const float* __restrict__ k, const float* __restrict__ v,
    const float* __restrict__ sq_raw1, const float* __restrict__ sq_b1,
    const float* __restrict__ sq_raw2, const float* __restrict__ sq_b2,
    const float* __restrict__ sk_raw1, const float* __restrict__ sk_b1,
    const float* __restrict__ sk_raw2, const float* __restrict__ sk_b2,
    const float* __restrict__ Wh, const float* __restrict__ Wv,
    float* __restrict__ fq, float* __restrict__ gk, float* __restrict__ gkpart,
    float* __restrict__ phiq, float* __restrict__ phik, float* __restrict__ uexp)
{
    __shared__ float xs[32 * 68];     // X tile, later z1 tile
    __shared__ float wb[64 * 68];     // softplus(W1)^T then softplus(W2)^T, [i][j]
    __shared__ float wh[64 * 36];     // Wh^T / Wv^T, [i][p]
    __shared__ float part[32 * 17];
    __shared__ float bb1[64], bb2[64];

    const int bx   = blockIdx.x;
    const int role = bx >> 7;
    const int sub  = bx & 127;
    const int g0   = sub * 32;
    const int tid  = threadIdx.x;
    const int tr = tid >> 4, tc = tid & 15;
    const int m0 = tr * 2, n0 = tc * 4, p0 = tc * 2;

    const float* xin = (role == 0) ? q : (role == 1) ? k : v;

    // ---- stage X (32x64): coalesced b128 reads, b128 writes ----
    const float4* xsrc = (const float4*)(xin + g0 * 64);
    #pragma unroll
    for (int c = 0; c < 2; ++c) {
        int idx4 = tid + c * 256;
        int t = idx4 >> 4, ic = (idx4 & 15) * 4;
        *(float4*)&xs[t * 68 + ic] = xsrc[idx4];
    }
    // ---- stage Wh/Wv: coalesced b128 read of natural [p][i], transposed
    //      scalar writes -> wh[i][p] (one-time 8-way conflict: negligible) ----
    const float4* whsrc = (const float4*)((role == 2) ? Wv : Wh);
    #pragma unroll
    for (int c = 0; c < 2; ++c) {
        int idx4 = tid + c * 256;
        int p = idx4 >> 4, i0 = (idx4 & 15) * 4;
        float4 w = whsrc[idx4];
        wh[(i0 + 0) * 36 + p] = w.x;
        wh[(i0 + 1) * 36 + p] = w.y;
        wh[(i0 + 2) * 36 + p] = w.z;
        wh[(i0 + 3) * 36 + p] = w.w;
    }
    float4 rw2[4];   // raw W2 prefetch (softplus'd + transposed at mid-phase)
    if (role < 2) {
        const float4* r1src = (const float4*)(role == 0 ? sq_raw1 : sk_raw1);
        const float4* r2src = (const float4*)(role == 0 ? sq_raw2 : sk_raw2);
        #pragma unroll
        for (int c = 0; c < 4; ++c) {
            int idx4 = tid + c * 256;
            int j = idx4 >> 4, i0 = (idx4 & 15) * 4;
            float4 w = r1src[idx4];
            wb[(i0 + 0) * 68 + j] = softplusf(w.x);
            wb[(i0 + 1) * 68 + j] = softplusf(w.y);
            wb[(i0 + 2) * 68 + j] = softplusf(w.z);
            wb[(i0 + 3) * 68 + j] = softplusf(w.w);
            rw2[c] = r2src[idx4];            // prefetch, no transcendental yet
        }
        if (tid < 64)       bb1[tid]      = (role == 0 ? sq_b1 : sk_b1)[tid];
        else if (tid < 128) bb2[tid - 64] = (role == 0 ? sq_b2 : sk_b2)[tid - 64];
    }
    __syncthreads();

    if (role == 2) {
        float acc[2][2] = {{0.f,0.f},{0.f,0.f}};
        #pragma unroll
        for (int kc = 0; kc < 16; ++kc) {
            const int i0 = kc * 4;
            float4 xv[2]; float2 hv[4];
            xv[0] = *(const float4*)&xs[(m0 + 0) * 68 + i0];
            xv[1] = *(const float4*)&xs[(m0 + 1) * 68 + i0];
            #pragma unroll
            for (int kk = 0; kk < 4; ++kk) hv[kk] = *(const float2*)&wh[(i0 + kk) * 36 + p0];
            #pragma unroll
            for (int mm = 0; mm < 2; ++mm) {
                const float* xa = (const float*)&xv[mm];
                #pragma unroll
                for (int kk = 0; kk < 4; ++kk) {
                    acc[mm][0] += xa[kk] * hv[kk].x;
                    acc[mm][1] += xa[kk] * hv[kk].y;
                }
            }
        }
        #pragma unroll
        for (int mm = 0; mm < 2; ++mm) {
            float2 o; o.x = __expf(acc[mm][0]); o.y = __expf(acc[mm][1]);
            *(float2*)&uexp[(g0 + m0 + mm) * 32 + p0] = o;
        }
        return;   // divergence only at block granularity
    }

    // ---- layer 1 + phi fused (transposed reads: conflict-free) ----
    float acc[2][4], accp[2][2];
    #pragma unroll
    for (int mm = 0; mm < 2; ++mm) {
        #pragma unroll
        for (int j = 0; j < 4; ++j) acc[mm][j] = bb1[n0 + j];
        accp[mm][0] = 0.f; accp[mm][1] = 0.f;
    }
    #pragma unroll
    for (int kc = 0; kc < 16; ++kc) {
        const int i0 = kc * 4;
        float4 xv[2], wv[4]; float2 hv[4];
        xv[0] = *(const float4*)&xs[(m0 + 0) * 68 + i0];
        xv[1] = *(const float4*)&xs[(m0 + 1) * 68 + i0];
        #pragma unroll
        for (int kk = 0; kk < 4; ++kk) {
            wv[kk] = *(const float4*)&wb[(i0 + kk) * 68 + n0];
            hv[kk] = *(const float2*)&wh[(i0 + kk) * 36 + p0];
        }
        #pragma unroll
        for (int mm = 0; mm < 2; ++mm) {
            const float* xa = (const float*)&xv[mm];
            #pragma unroll
            for (int kk = 0; kk < 4; ++kk) {
                const float xmk = xa[kk];
                const float* wa = (const float*)&wv[kk];
                acc[mm][0] += xmk * wa[0];
                acc[mm][1] += xmk * wa[1];
                acc[mm][2] += xmk * wa[2];
                acc[mm][3] += xmk * wa[3];
                accp[mm][0] += xmk * hv[kk].x;
                accp[mm][1] += xmk * hv[kk].y;
            }
        }
    }
    float* phiout = (role == 0) ? phiq : phik;
    #pragma unroll
    for (int mm = 0; mm < 2; ++mm) {
        float2 o; o.x = __expf(accp[mm][0]); o.y = __expf(accp[mm][1]);
        *(float2*)&phiout[(g0 + m0 + mm) * 32 + p0] = o;
    }
    float z1v[2][4];
    #pragma unroll
    for (int mm = 0; mm < 2; ++mm)
        #pragma unroll
        for (int j = 0; j < 4; ++j) z1v[mm][j] = softplusf(acc[mm][j]);
    __syncthreads();
    // z1 -> xs ; softplus(W2 prefetch) -> wb transposed (one-time writes)
    #pragma unroll
    for (int mm = 0; mm < 2; ++mm)
        *(float4*)&xs[(m0 + mm) * 68 + n0] = *(float4*)&z1v[mm][0];
    #pragma unroll
    for (int c = 0; c < 4; ++c) {
        int idx4 = tid + c * 256;
        int j = idx4 >> 4, i0 = (idx4 & 15) * 4;
        float4 w = rw2[c];
        wb[(i0 + 0) * 68 + j] = softplusf(w.x);
        wb[(i0 + 1) * 68 + j] = softplusf(w.y);
        wb[(i0 + 2) * 68 + j] = softplusf(w.z);
        wb[(i0 + 3) * 68 + j] = softplusf(w.w);
    }
    __syncthreads();

    // ---- layer 2 ----
    float acc2[2][4];
    #pragma unroll
    for (int mm = 0; mm < 2; ++mm)
        #pragma unroll
        for (int j = 0; j < 4; ++j) acc2[mm][j] = bb2[n0 + j];
    #pragma unroll
    for (int kc = 0; kc < 16; ++kc) {
        const int i0 = kc * 4;
        float4 xv[2], wv[4];
        xv[0] = *(const float4*)&xs[(m0 + 0) * 68 + i0];
        xv[1] = *(const float4*)&xs[(m0 + 1) * 68 + i0];
        #pragma unroll
        for (int kk = 0; kk < 4; ++kk) wv[kk] = *(const float4*)&wb[(i0 + kk) * 68 + n0];
        #pragma unroll
        for (int mm = 0; mm < 2; ++mm) {
            const float* xa = (const float*)&xv[mm];
            #pragma unroll
            for (int kk = 0; kk < 4; ++kk) {
                const float xmk = xa[kk];
                const float* wa = (const float*)&wv[kk];
                acc2[mm][0] += xmk * wa[0];
                acc2[mm][1] += xmk * wa[1];
                acc2[mm][2] += xmk * wa[2];
                acc2[mm][3] += xmk * wa[3];
            }
        }
    }
    #pragma unroll
    for (int mm = 0; mm < 2; ++mm) {
        float s = softplusf(acc2[mm][0]) + softplusf(acc2[mm][1])
                + softplusf(acc2[mm][2]) + softplusf(acc2[mm][3]);
        part[(m0 + mm) * 17 + tc] = s;
    }
    __syncthreads();
    if (tid < 32) {
        float s = 0.f;
        #pragma unroll
        for (int c = 0; c < 16; ++c) s += part[tid * 17 + c];
        if (role == 0) fq[g0 + tid] = s;
        else           gk[g0 + tid] = s;
        if (role == 1) {
            float mx = s;
            #pragma unroll
            for (int off = 16; off >= 1; off >>= 1)
                mx = fmaxf(mx, __shfl_xor(mx, off, 32));
            if (tid == 0) gkpart[sub] = mx;
        }
    }
}

// ---------------------------------------------------------------------------
// Kernel 2 v3: partial factorized reduction. Grid = 64 (8 heads x 8 chunks
// of 64 t). G = exact per-head max from gkpart (16 block-partials).
//   Mpart[bx][r][p] = sum_{t in chunk} phik[t,r] * exp(gk[t]-G) * uexp[t,p]
// ---------------------------------------------------------------------------
__global__ __launch_bounds__(256) void csm_reduceM(
    const float* __restrict__ gk, const float* __restrict__ gkpart,
    const float* __restrict__ phik, const float* __restrict__ uexp,
    float* __restrict__ Mpart, float* __restrict__ Gbuf)
{
    __shared__ float wls[64];
    __shared__ float pk[64 * 36];
    __shared__ float wu[64 * 36];

    const int h     = blockIdx.x >> 3;
    const int chunk = blockIdx.x & 7;
    const int tid   = threadIdx.x;
    const int t0    = chunk * 64;

    float G = gkpart[h * 16];
    #pragma unroll
    for (int i = 1; i < 16; ++i) G = fmaxf(G, gkpart[h * 16 + i]);
    if (chunk == 0 && tid == 0) Gbuf[h] = G;

    if (tid < 64) wls[tid] = __expf(gk[h * SS + t0 + tid] - G);
    __syncthreads();

    const float4* psrc = (const float4*)(phik + (h * SS + t0) * PP);
    const float4* usrc = (const float4*)(uexp + (h * SS + t0) * PP);
    #pragma unroll
    for (int c = 0; c < 2; ++c) {
        int idx4 = tid + c * 256;
        int t = idx4 >> 3, pc = (idx4 & 7) * 4;
        *(float4*)&pk[t * 36 + pc] = psrc[idx4];
        float4 uv = usrc[idx4];
        float w = wls[t];
        uv.x *= w; uv.y *= w; uv.z *= w; uv.w *= w;
        *(float4*)&wu[t * 36 + pc] = uv;
    }
    __syncthreads();

    const int r0 = (tid >> 5) * 4, p = tid & 31;
    float macc[4] = {0.f, 0.f, 0.f, 0.f};
    for (int t = 0; t < 64; ++t) {
        const float wup = wu[t * 36 + p];
        const float4 pv = *(const float4*)&pk[t * 36 + r0];
        macc[0] += pv.x * wup;
        macc[1] += pv.y * wup;
        macc[2] += pv.z * wup;
        macc[3] += pv.w * wup;
    }
    float* mp = Mpart + blockIdx.x * 1024;
    #pragma unroll
    for (int rr = 0; rr < 4; ++rr)
        mp[(r0 + rr) * 32 + p] = macc[rr];
}

// ---------------------------------------------------------------------------
// Kernel 3: output. Sums the 8 M-partials of its head, then
//   y[s,p] = log( phi_q[s] . M[:,p] ) + f_q[s] + G - log S
// Grid = 512 blocks x 256 threads; block = 8 consecutive tokens x 32 p.
// ---------------------------------------------------------------------------
__global__ __launch_bounds__(256) void csm_out(
    const float* __restrict__ fq, const float* __restrict__ phiq,
    const float* __restrict__ Mpart, const float* __restrict__ Gbuf,
    float* __restrict__ y)
{
    __shared__ float Ms[32 * 36];
    __shared__ float pqs[8 * 32];
    __shared__ float fqs[8];

    const int bx = blockIdx.x;
    const int s0 = bx * 8;           // global token index (h*512+s)
    const int h  = bx >> 6;
    const int tid = threadIdx.x;

    {
        const int e = tid * 4;
        const float* base = Mpart + h * 8 * 1024 + e;
        float4 s = *(const float4*)(base);
        #pragma unroll
        for (int c = 1; c < 8; ++c) {
            float4 a = *(const float4*)(base + c * 1024);
            s.x += a.x; s.y += a.y; s.z += a.z; s.w += a.w;
        }
        *(float4*)&Ms[(tid >> 3) * 36 + (tid & 7) * 4] = s;
    }
    pqs[tid] = phiq[s0 * 32 + tid];
    if (tid < 8) fqs[tid] = fq[s0 + tid];
    __syncthreads();

    const int si = tid >> 5, p = tid & 31;
    float acc = 0.f;
    #pragma unroll
    for (int rc = 0; rc < 8; ++rc) {
        const float4 pq = *(const float4*)&pqs[si * 32 + rc * 4];
        acc += pq.x * Ms[(rc * 4 + 0) * 36 + p];
        acc += pq.y * Ms[(rc * 4 + 1) * 36 + p];
        acc += pq.z * Ms[(rc * 4 + 2) * 36 + p];
        acc += pq.w * Ms[(rc * 4 + 3) * 36 + p];
    }
    const float LOG_S = 6.2383246250395078f;   // log(512)
    y[(s0 + si) * 32 + p] = __logf(acc) + fqs[si] + Gbuf[h] - LOG_S;
}

extern "C" void kernel_launch(void* const* d_in, const int* in_sizes, int n_in,
                              void* d_out, int out_size, void* d_ws, size_t ws_size,
                              hipStream_t stream) {
    (void)in_sizes; (void)n_in; (void)out_size; (void)ws_size;
    const float* q       = (const float*)d_in[0];
    const float* k       = (const float*)d_in[1];
    const float* v       = (const float*)d_in[2];
    const float* sq_raw1 = (const float*)d_in[3];
    const float* sq_b1   = (const float*)d_in[4];
    const float* sq_raw2 = (const float*)d_in[5];
    const float* sq_b2   = (const float*)d_in[6];
    const float* sk_raw1 = (const float*)d_in[7];
    const float* sk_b1   = (const float*)d_in[8];
    const float* sk_raw2 = (const float*)d_in[9];
    const float* sk_b2   = (const float*)d_in[10];
    const float* Wh      = (const float*)d_in[11];
    const float* Wv      = (const float*)d_in[12];
    float* y = (float*)d_out;

    float* ws     = (float*)d_ws;
    float* fq     = ws;                  // 4096
    float* gk     = ws + 4096;           // 4096
    float* gkpart = ws + 8192;           // 128
    float* Gbuf   = ws + 8320;           // 8 (+pad)
    float* phiq   = ws + 8448;           // 131072
    float* phik   = ws + 139520;         // 131072
    float* uexp   = ws + 270592;         // 131072
    float* Mpart  = ws + 401664;         // 65536

    csm_token5<<<384, 256, 0, stream>>>(q, k, v,
                                        sq_raw1, sq_b1, sq_raw2, sq_b2,
                                        sk_raw1, sk_b1, sk_raw2, sk_b2,
                                        Wh, Wv,
                                        fq, gk, gkpart, phiq, phik, uexp);
    csm_reduceM<<<64, 256, 0, stream>>>(gk, gkpart, phik, uexp, Mpart, Gbuf);
    csm_out<<<512, 256, 0, stream>>>(fq, phiq, Mpart, Gbuf, y);
}

// Round 9
// 102.294 us; speedup vs baseline: 1.0567x; 1.0567x over previous
//
#include <hip/hip_runtime.h>
#include <math.h>

// Problem constants: B=1, H=8, S=512, D=64, P=32
#define HH 8
#define SS 512
#define DD 64
#define PP 32

// NOTE (R5-R8 findings — the journal):
//  * Total dur_us carries ~81 us of fixed harness overhead — two ~40 us 0xAA
//    poison fills of the 256 MB workspace (fillBufferAligned at ~84% HBM peak)
//    inside the timed window. Kernel-side work is only ~22 us. Don't chase it.
//  * Keep ICNN weights TRANSPOSED in LDS ([in][out], pad 68): natural [out][in]
//    rows n0=4*tc at stride 68 collapse to banks {0,16} = 8-way conflict
//    (R6: +7 us). Padding can't fix it (float4 alignment forces stride%4==0).
//  * Do NOT fuse the weight prep into the token kernel: per-block re-softplus
//    of 8K weights (log1pf on the pre-barrier critical path) + scalar LDS
//    transpose writes cost ~+5 us even with conflict-free k-loops (R8).
//    One-time prep through global memory (this file) is the right division.
//  * No min-waves launch-bounds arg on the token kernel — R4 showed (256,4)
//    forces VGPR=64 and spills ~575 MB scratch (268 us).

__device__ __forceinline__ float softplusf(float x) {
    if (x > 20.f) return x;
    return log1pf(__expf(x));
}

// ---------------------------------------------------------------------------
// Kernel 0: one-time weight prep (softplus + transpose into wbuf).
//   [0..4096)      w1qT   [4096..8192)   w2qT
//   [8192..12288)  w1kT   [12288..16384) w2kT
//   [16384..18432) whT    [18432..20480) wvT
// ---------------------------------------------------------------------------
__global__ __launch_bounds__(256) void csm_prep(
    const float* __restrict__ sq1, const float* __restrict__ sq2,
    const float* __restrict__ sk1, const float* __restrict__ sk2,
    const float* __restrict__ Wh, const float* __restrict__ Wv,
    float* __restrict__ wbuf)
{
    int idx = blockIdx.x * 256 + threadIdx.x;   // grid = 80 blocks -> 20480
    if (idx < 16384) {
        int m = idx >> 12, r = idx & 4095;
        int i = r >> 6, j = r & 63;             // dest [i][j] = softplus(src[j][i])
        const float* src = (m == 0) ? sq1 : (m == 1) ? sq2 : (m == 2) ? sk1 : sk2;
        wbuf[idx] = softplusf(src[j * 64 + i]);
    } else if (idx < 18432) {
        int r = idx - 16384; int i = r >> 5, p = r & 31;
        wbuf[idx] = Wh[p * 64 + i];
    } else if (idx < 20480) {
        int r = idx - 18432; int i = r >> 5, p = r & 31;
        wbuf[idx] = Wv[p * 64 + i];
    }
}

// ---------------------------------------------------------------------------
// Kernel 1: per-token compute. 32 tokens/block -> 384 blocks.
// role = bx>>7: 0=q (fq, phiq), 1=k (gk, phik, gkpart), 2=v (uexp).
// 256 threads = 16x16; thread tile = 2 tokens x 4 outputs (x2 p for phi).
// W1 and W2 staged sequentially through ONE LDS buffer (38 KB).
// ---------------------------------------------------------------------------
__global__ __launch_bounds__(256) void csm_token3(
    const float* __restrict__ q, const float* __restrict__ k, const float* __restrict__ v,
    const float* __restrict__ sq_b1, const float* __restrict__ sq_b2,
    const float* __restrict__ sk_b1, const float* __restrict__ sk_b2,
    const float* __restrict__ wbuf,
    float* __restrict__ fq, float* __restrict__ gk, float* __restrict__ gkpart,
    float* __restrict__ phiq, float* __restrict__ phik, float* __restrict__ uexp)
{
    __shared__ float xs[32 * 68];     // X tile, later z1 tile
    __shared__ float wb[64 * 68];     // W1T then W2T
    __shared__ float wh[64 * 36];     // WhT / WvT
    __shared__ float part[32 * 17];
    __shared__ float bb1[64], bb2[64];

    const int bx   = blockIdx.x;
    const int role = bx >> 7;
    const int sub  = bx & 127;
    const int g0   = sub * 32;
    const int tid  = threadIdx.x;
    const int tr = tid >> 4, tc = tid & 15;
    const int m0 = tr * 2, n0 = tc * 4, p0 = tc * 2;

    const float* xin = (role == 0) ? q : (role == 1) ? k : v;

    // ---- stage X (32x64) ----
    const float4* xsrc = (const float4*)(xin + g0 * 64);
    #pragma unroll
    for (int c = 0; c < 2; ++c) {
        int idx4 = tid + c * 256;
        int t = idx4 >> 4, ic = (idx4 & 15) * 4;
        *(float4*)&xs[t * 68 + ic] = xsrc[idx4];
    }
    // ---- stage projection weights (64x32, transposed [i][p]) ----
    const float4* whsrc = (const float4*)(wbuf + ((role == 2) ? 18432 : 16384));
    #pragma unroll
    for (int c = 0; c < 2; ++c) {
        int idx4 = tid + c * 256;
        int i = idx4 >> 3, pc = (idx4 & 7) * 4;
        *(float4*)&wh[i * 36 + pc] = whsrc[idx4];
    }
    if (role < 2) {
        const float4* w1src = (const float4*)(wbuf + (role == 0 ? 0 : 8192));
        #pragma unroll
        for (int c = 0; c < 4; ++c) {
            int idx4 = tid + c * 256;
            int i = idx4 >> 4, jc = (idx4 & 15) * 4;
            *(float4*)&wb[i * 68 + jc] = w1src[idx4];
        }
        if (tid < 64)       bb1[tid]      = (role == 0 ? sq_b1 : sk_b1)[tid];
        else if (tid < 128) bb2[tid - 64] = (role == 0 ? sq_b2 : sk_b2)[tid - 64];
    }
    __syncthreads();

    if (role == 2) {
        float acc[2][2] = {{0.f,0.f},{0.f,0.f}};
        #pragma unroll
        for (int kc = 0; kc < 16; ++kc) {
            const int i0 = kc * 4;
            float4 xv[2]; float2 hv[4];
            xv[0] = *(const float4*)&xs[(m0 + 0) * 68 + i0];
            xv[1] = *(const float4*)&xs[(m0 + 1) * 68 + i0];
            #pragma unroll
            for (int kk = 0; kk < 4; ++kk) hv[kk] = *(const float2*)&wh[(i0 + kk) * 36 + p0];
            #pragma unroll
            for (int mm = 0; mm < 2; ++mm) {
                const float* xa = (const float*)&xv[mm];
                #pragma unroll
                for (int kk = 0; kk < 4; ++kk) {
                    acc[mm][0] += xa[kk] * hv[kk].x;
                    acc[mm][1] += xa[kk] * hv[kk].y;
                }
            }
        }
        #pragma unroll
        for (int mm = 0; mm < 2; ++mm) {
            float2 o; o.x = __expf(acc[mm][0]); o.y = __expf(acc[mm][1]);
            *(float2*)&uexp[(g0 + m0 + mm) * 32 + p0] = o;
        }
        return;   // divergence only at block granularity
    }

    // ---- layer 1 + phi fused ----
    float acc[2][4], accp[2][2];
    #pragma unroll
    for (int mm = 0; mm < 2; ++mm) {
        #pragma unroll
        for (int j = 0; j < 4; ++j) acc[mm][j] = bb1[n0 + j];
        accp[mm][0] = 0.f; accp[mm][1] = 0.f;
    }
    #pragma unroll
    for (int kc = 0; kc < 16; ++kc) {
        const int i0 = kc * 4;
        float4 xv[2], wv[4]; float2 hv[4];
        xv[0] = *(const float4*)&xs[(m0 + 0) * 68 + i0];
        xv[1] = *(const float4*)&xs[(m0 + 1) * 68 + i0];
        #pragma unroll
        for (int kk = 0; kk < 4; ++kk) {
            wv[kk] = *(const float4*)&wb[(i0 + kk) * 68 + n0];
            hv[kk] = *(const float2*)&wh[(i0 + kk) * 36 + p0];
        }
        #pragma unroll
        for (int mm = 0; mm < 2; ++mm) {
            const float* xa = (const float*)&xv[mm];
            #pragma unroll
            for (int kk = 0; kk < 4; ++kk) {
                const float xmk = xa[kk];
                const float* wa = (const float*)&wv[kk];
                acc[mm][0] += xmk * wa[0];
                acc[mm][1] += xmk * wa[1];
                acc[mm][2] += xmk * wa[2];
                acc[mm][3] += xmk * wa[3];
                accp[mm][0] += xmk * hv[kk].x;
                accp[mm][1] += xmk * hv[kk].y;
            }
        }
    }
    float* phiout = (role == 0) ? phiq : phik;
    #pragma unroll
    for (int mm = 0; mm < 2; ++mm) {
        float2 o; o.x = __expf(accp[mm][0]); o.y = __expf(accp[mm][1]);
        *(float2*)&phiout[(g0 + m0 + mm) * 32 + p0] = o;
    }
    float z1v[2][4];
    #pragma unroll
    for (int mm = 0; mm < 2; ++mm)
        #pragma unroll
        for (int j = 0; j < 4; ++j) z1v[mm][j] = softplusf(acc[mm][j]);
    __syncthreads();
    // z1 -> xs ; W2 -> wb (W1 reads all completed above)
    #pragma unroll
    for (int mm = 0; mm < 2; ++mm)
        *(float4*)&xs[(m0 + mm) * 68 + n0] = *(float4*)&z1v[mm][0];
    {
        const float4* w2src = (const float4*)(wbuf + (role == 0 ? 4096 : 12288));
        #pragma unroll
        for (int c = 0; c < 4; ++c) {
            int idx4 = tid + c * 256;
            int i = idx4 >> 4, jc = (idx4 & 15) * 4;
            *(float4*)&wb[i * 68 + jc] = w2src[idx4];
        }
    }
    __syncthreads();

    // ---- layer 2 ----
    float acc2[2][4];
    #pragma unroll
    for (int mm = 0; mm < 2; ++mm)
        #pragma unroll
        for (int j = 0; j < 4; ++j) acc2[mm][j] = bb2[n0 + j];
    #pragma unroll
    for (int kc = 0; kc < 16; ++kc) {
        const int i0 = kc * 4;
        float4 xv[2], wv[4];
        xv[0] = *(const float4*)&xs[(m0 + 0) * 68 + i0];
        xv[1] = *(const float4*)&xs[(m0 + 1) * 68 + i0];
        #pragma unroll
        for (int kk = 0; kk < 4; ++kk) wv[kk] = *(const float4*)&wb[(i0 + kk) * 68 + n0];
        #pragma unroll
        for (int mm = 0; mm < 2; ++mm) {
            const float* xa = (const float*)&xv[mm];
            #pragma unroll
            for (int kk = 0; kk < 4; ++kk) {
                const float xmk = xa[kk];
                const float* wa = (const float*)&wv[kk];
                acc2[mm][0] += xmk * wa[0];
                acc2[mm][1] += xmk * wa[1];
                acc2[mm][2] += xmk * wa[2];
                acc2[mm][3] += xmk * wa[3];
            }
        }
    }
    #pragma unroll
    for (int mm = 0; mm < 2; ++mm) {
        float s = softplusf(acc2[mm][0]) + softplusf(acc2[mm][1])
                + softplusf(acc2[mm][2]) + softplusf(acc2[mm][3]);
        part[(m0 + mm) * 17 + tc] = s;
    }
    __syncthreads();
    if (tid < 32) {
        float s = 0.f;
        #pragma unroll
        for (int c = 0; c < 16; ++c) s += part[tid * 17 + c];
        if (role == 0) fq[g0 + tid] = s;
        else           gk[g0 + tid] = s;
        if (role == 1) {
            float mx = s;
            #pragma unroll
            for (int off = 16; off >= 1; off >>= 1)
                mx = fmaxf(mx, __shfl_xor(mx, off, 32));
            if (tid == 0) gkpart[sub] = mx;
        }
    }
}

// ---------------------------------------------------------------------------
// Kernel 2: partial factorized reduction. Grid = 32 (8 heads x 4 chunks
// of 128 t). G = exact per-head max from gkpart (16 block-partials).
//   Mpart[bx][r][p] = sum_{t in chunk} phik[t,r] * exp(gk[t]-G) * uexp[t,p]
// ---------------------------------------------------------------------------
__global__ __launch_bounds__(256) void csm_reduceM(
    const float* __restrict__ gk, const float* __restrict__ gkpart,
    const float* __restrict__ phik, const float* __restrict__ uexp,
    float* __restrict__ Mpart, float* __restrict__ Gbuf)
{
    __shared__ float wls[128];
    __shared__ float pk[128 * 36];
    __shared__ float wu[128 * 36];

    const int h     = blockIdx.x >> 2;
    const int chunk = blockIdx.x & 3;
    const int tid   = threadIdx.x;
    const int t0    = chunk * 128;

    float G = gkpart[h * 16];
    #pragma unroll
    for (int i = 1; i < 16; ++i) G = fmaxf(G, gkpart[h * 16 + i]);
    if (chunk == 0 && tid == 0) Gbuf[h] = G;

    if (tid < 128) wls[tid] = __expf(gk[h * SS + t0 + tid] - G);
    __syncthreads();

    const float4* psrc = (const float4*)(phik + (h * SS + t0) * PP);
    const float4* usrc = (const float4*)(uexp + (h * SS + t0) * PP);
    #pragma unroll
    for (int c = 0; c < 4; ++c) {
        int idx4 = tid + c * 256;
        int t = idx4 >> 3, pc = (idx4 & 7) * 4;
        *(float4*)&pk[t * 36 + pc] = psrc[idx4];
        float4 uv = usrc[idx4];
        float w = wls[t];
        uv.x *= w; uv.y *= w; uv.z *= w; uv.w *= w;
        *(float4*)&wu[t * 36 + pc] = uv;
    }
    __syncthreads();

    const int r0 = (tid >> 5) * 4, p = tid & 31;
    float macc[4] = {0.f, 0.f, 0.f, 0.f};
    for (int t = 0; t < 128; ++t) {
        const float wup = wu[t * 36 + p];
        const float4 pv = *(const float4*)&pk[t * 36 + r0];
        macc[0] += pv.x * wup;
        macc[1] += pv.y * wup;
        macc[2] += pv.z * wup;
        macc[3] += pv.w * wup;
    }
    float* mp = Mpart + blockIdx.x * 1024;
    #pragma unroll
    for (int rr = 0; rr < 4; ++rr)
        mp[(r0 + rr) * 32 + p] = macc[rr];
}

// ---------------------------------------------------------------------------
// Kernel 3: output. Sums the 4 M-partials of its head, then
//   y[s,p] = log( phi_q[s] . M[:,p] ) + f_q[s] + G - log S
// Grid = 512 blocks x 256 threads; block = 8 consecutive tokens x 32 p.
// ---------------------------------------------------------------------------
__global__ __launch_bounds__(256) void csm_out(
    const float* __restrict__ fq, const float* __restrict__ phiq,
    const float* __restrict__ Mpart, const float* __restrict__ Gbuf,
    float* __restrict__ y)
{
    __shared__ float Ms[32 * 36];
    __shared__ float pqs[8 * 32];
    __shared__ float fqs[8];

    const int bx = blockIdx.x;
    const int s0 = bx * 8;           // global token index (h*512+s)
    const int h  = bx >> 6;
    const int tid = threadIdx.x;

    {
        const int e = tid * 4;
        const float* base = Mpart + h * 4 * 1024 + e;
        float4 a = *(const float4*)(base);
        float4 b = *(const float4*)(base + 1024);
        float4 c = *(const float4*)(base + 2048);
        float4 d = *(const float4*)(base + 3072);
        float4 s;
        s.x = a.x + b.x + c.x + d.x;
        s.y = a.y + b.y + c.y + d.y;
        s.z = a.z + b.z + c.z + d.z;
        s.w = a.w + b.w + c.w + d.w;
        *(float4*)&Ms[(tid >> 3) * 36 + (tid & 7) * 4] = s;
    }
    pqs[tid] = phiq[s0 * 32 + tid];
    if (tid < 8) fqs[tid] = fq[s0 + tid];
    __syncthreads();

    const int si = tid >> 5, p = tid & 31;
    float acc = 0.f;
    #pragma unroll
    for (int rc = 0; rc < 8; ++rc) {
        const float4 pq = *(const float4*)&pqs[si * 32 + rc * 4];
        acc += pq.x * Ms[(rc * 4 + 0) * 36 + p];
        acc += pq.y * Ms[(rc * 4 + 1) * 36 + p];
        acc += pq.z * Ms[(rc * 4 + 2) * 36 + p];
        acc += pq.w * Ms[(rc * 4 + 3) * 36 + p];
    }
    const float LOG_S = 6.2383246250395078f;   // log(512)
    y[(s0 + si) * 32 + p] = __logf(acc) + fqs[si] + Gbuf[h] - LOG_S;
}

extern "C" void kernel_launch(void* const* d_in, const int* in_sizes, int n_in,
                              void* d_out, int out_size, void* d_ws, size_t ws_size,
                              hipStream_t stream) {
    (void)in_sizes; (void)n_in; (void)out_size; (void)ws_size;
    const float* q       = (const float*)d_in[0];
    const float* k       = (const float*)d_in[1];
    const float* v       = (const float*)d_in[2];
    const float* sq_raw1 = (const float*)d_in[3];
    const float* sq_b1   = (const float*)d_in[4];
    const float* sq_raw2 = (const float*)d_in[5];
    const float* sq_b2   = (const float*)d_in[6];
    const float* sk_raw1 = (const float*)d_in[7];
    const float* sk_b1   = (const float*)d_in[8];
    const float* sk_raw2 = (const float*)d_in[9];
    const float* sk_b2   = (const float*)d_in[10];
    const float* Wh      = (const float*)d_in[11];
    const float* Wv      = (const float*)d_in[12];
    float* y = (float*)d_out;

    float* ws     = (float*)d_ws;
    float* wbuf   = ws;                  // 20480
    float* fq     = ws + 20480;          // 4096
    float* gk     = ws + 24576;          // 4096
    float* gkpart = ws + 28672;          // 128
    float* Gbuf   = ws + 28800;          // 8
    float* phiq   = ws + 28928;          // 131072
    float* phik   = ws + 160000;         // 131072
    float* uexp   = ws + 291072;         // 131072
    float* Mpart  = ws + 422144;         // 32768

    csm_prep<<<80, 256, 0, stream>>>(sq_raw1, sq_raw2, sk_raw1, sk_raw2, Wh, Wv, wbuf);
    csm_token3<<<384, 256, 0, stream>>>(q, k, v, sq_b1, sq_b2, sk_b1, sk_b2,
                                        wbuf, fq, gk, gkpart, phiq, phik, uexp);
    csm_reduceM<<<32, 256, 0, stream>>>(gk, gkpart, phik, uexp, Mpart, Gbuf);
    csm_out<<<512, 256, 0, stream>>>(fq, phiq, Mpart, Gbuf, y);
}